// Round 10
// baseline (1439.071 us; speedup 1.0000x reference)
//
#include <hip/hip_runtime.h>

#define HID_ 1000
#define NB 256
#define TT 49
#define DIN 192
#define NPAD 1024
#define M_ALL (TT * 256)  // 12544

typedef _Float16 f16;
typedef _Float16 f16x4 __attribute__((ext_vector_type(4)));
typedef _Float16 f16x8 __attribute__((ext_vector_type(8)));
typedef float f32x4 __attribute__((ext_vector_type(4)));
typedef const __attribute__((address_space(1))) unsigned int* gas_u32;
typedef __attribute__((address_space(3))) unsigned int* las_u32;

__device__ __forceinline__ float sigmf_(float x) {
    return 1.0f / (1.0f + __expf(-x));
}
__device__ __forceinline__ float tanhf_(float x) {
    float ax = fabsf(x);
    float e = __expf(-2.0f * ax);
    float t = (1.0f - e) / (1.0f + e);
    return copysignf(t, x);
}

// Convert fp32 weight [4*HID_][K] -> f16 [4][NPAD][KPADv], zero-padded.
__global__ void conv_weight(const float* __restrict__ src, f16* __restrict__ dst,
                            int K, int KPADv) {
    size_t total = 4ull * NPAD * KPADv;
    for (size_t idx = (size_t)blockIdx.x * blockDim.x + threadIdx.x; idx < total;
         idx += (size_t)gridDim.x * blockDim.x) {
        int kp = (int)(idx % KPADv);
        size_t rest = idx / KPADv;
        int np = (int)(rest % NPAD);
        int g = (int)(rest / NPAD);
        f16 v = (f16)0.0f;
        if (np < HID_ && kp < K) v = (f16)src[(size_t)(g * HID_ + np) * K + kp];
        dst[idx] = v;
    }
}

// enc_in [B][T][D] fp32 -> xbf [T][B][D] f16
__global__ void conv_x(const float* __restrict__ src, f16* __restrict__ dst) {
    size_t total = (size_t)TT * NB * DIN;
    for (size_t idx = (size_t)blockIdx.x * blockDim.x + threadIdx.x; idx < total;
         idx += (size_t)gridDim.x * blockDim.x) {
        int k = (int)(idx % DIN);
        size_t rest = idx / DIN;
        int b = (int)(rest % NB);
        int t = (int)(rest / NB);
        dst[idx] = (f16)src[((size_t)b * TT + t) * DIN + k];
    }
}

// bias_c[4][NPAD] fp32 = b_ih + b_hh (zero-padded)
__global__ void conv_bias(const float* __restrict__ bih, const float* __restrict__ bhh,
                          float* __restrict__ dst) {
    int idx = blockIdx.x * blockDim.x + threadIdx.x;
    if (idx < 4 * NPAD) {
        int np = idx & (NPAD - 1);
        int g = idx >> 10;
        float v = 0.0f;
        if (np < HID_) v = bih[g * HID_ + np] + bhh[g * HID_ + np];
        dst[idx] = v;
    }
}

// pre2 = A @ W^T + bias, stored in rec's fragment order:
// elem = [t][bt][jt] * 4096 + slot(=u*16+rcol)*64 + g*16 + n*8 + mi*4 + q   (f16)
__global__ __launch_bounds__(256) void input_gemm(
    const f16* __restrict__ A, int lda, int kiters,
    const f16* __restrict__ W, int ldw,
    const float* __restrict__ bias,
    f16* __restrict__ pre2) {
    __shared__ f16 As[128 * 64];
    __shared__ f16 Bs[128 * 64];
    const int id = blockIdx.x;
    const int sw = (id & 7) * (gridDim.x >> 3) + (id >> 3);  // XCD swizzle (3136%8==0)
    const int m0 = (sw >> 5) << 7;
    const int n0 = (sw & 31) << 7;
    const int w = threadIdx.x >> 6;
    const int lane = threadIdx.x & 63;
    const int r = lane & 15;
    const int u = lane >> 4;
    const int kb8 = u << 3;  // frag k-offset (elements)
    const int wm = (w >> 1) << 6, wn = (w & 1) << 6;
    const int strow = (w << 5) + (lane >> 3);  // + q*8
    const int stcol = (lane & 7) << 3;         // elements

    f32x4 acc[4][4];
#pragma unroll
    for (int i = 0; i < 4; i++)
#pragma unroll
        for (int j = 0; j < 4; j++) acc[i][j] = (f32x4){0.f, 0.f, 0.f, 0.f};

    for (int kt = 0; kt < kiters; kt++) {
        const int k0 = kt << 6;
#pragma unroll
        for (int q = 0; q < 4; q++) {
            const int row = strow + (q << 3);
            const int cbase = ((w << 5) + (q << 3)) << 6;  // wave-uniform chunk base (elems)
            const f16* ga = A + (size_t)(m0 + row) * lda + k0 + stcol;
            const f16* gb = W + (size_t)(n0 + row) * ldw + k0 + stcol;
            __builtin_amdgcn_global_load_lds((gas_u32)ga, (las_u32)(As + cbase), 16, 0, 0);
            __builtin_amdgcn_global_load_lds((gas_u32)gb, (las_u32)(Bs + cbase), 16, 0, 0);
        }
        __syncthreads();
#pragma unroll
        for (int ks = 0; ks < 2; ks++) {
            f16x8 av[4], bv[4];
#pragma unroll
            for (int i = 0; i < 4; i++)
                av[i] = *(const f16x8*)(As + ((wm + i * 16 + r) << 6) + (ks << 5) + kb8);
#pragma unroll
            for (int j = 0; j < 4; j++)
                bv[j] = *(const f16x8*)(Bs + ((wn + j * 16 + r) << 6) + (ks << 5) + kb8);
#pragma unroll
            for (int i = 0; i < 4; i++)
#pragma unroll
                for (int j = 0; j < 4; j++)
                    acc[i][j] = __builtin_amdgcn_mfma_f32_16x16x32_f16(av[i], bv[j], acc[i][j], 0, 0, 0);
        }
        __syncthreads();
    }

#pragma unroll
    for (int j = 0; j < 4; j++) {
        const int gcol = n0 + wn + j * 16 + r;
        const float bj = bias[gcol];
        const int g = gcol >> 10;
        const int cl = gcol & 1023;
        const int jt2 = cl >> 5;
        const int n2 = (cl >> 4) & 1;
#pragma unroll
        for (int i = 0; i < 4; i++) {
            const int grow = m0 + wm + i * 16 + (u << 2);  // q=0 row
            const int t_ = grow >> 8;
            const int bt2 = (grow >> 5) & 7;
            const int mi = i & 1;
            f16x4 hv;
#pragma unroll
            for (int q = 0; q < 4; q++) hv[q] = (f16)(acc[i][j][q] + bj);
            const int slot = (u << 4) + r;  // row-u x col-r
            *(f16x4*)(pre2 + (((size_t)t_ * 8 + bt2) * 32 + jt2) * 4096 +
                      (size_t)slot * 64 + g * 16 + n2 * 8 + mi * 4) = hv;
        }
    }
}

// Persistent per-layer recurrent kernel. 256 wgs x 512 thr, 1 wg/CU.
// wg (bt = bid&7, jt = bid>>3): 32 batches x 32 cols x 4 gates.
// Wave (gp 0..1, kh 0..3): gates {2gp,2gp+1}, k-quarter kh.
// h is loaded DIRECTLY from global (L2) into VGPR A-fragments — no LDS
// staging, no stage barrier, no A-side bank conflicts. LDS holds only the
// pl partial-combine. Per-quarter flags: wave kh waits only for the 8
// producers (jt>>3 == kh) of its k-quarter. Publish/consume mechanics
// (relaxed AGENT atomics, first-touch reads) identical to r5-r9 validated.
__global__ __launch_bounds__(512, 2) void rec_persist(
    const f16* __restrict__ Whh, const f16* __restrict__ pre2,
    f16* __restrict__ hall, float* __restrict__ outl,
    unsigned int* __restrict__ flags) {
    __shared__ float pl[4 * 4 * 32 * 34];  // [kh][gate][row][34] f32 partials
    const int bid = blockIdx.x;
    const int bt = bid & 7;    // batch group (XCD-local under round-robin)
    const int jt = bid >> 3;   // column tile 0..31
    const int b0 = bt << 5;
    const int jc0 = jt << 5;
    const int tid = threadIdx.x;
    const int w = tid >> 6;
    const int gp = w >> 2;     // gate pair 0..1
    const int kh = w & 3;      // k-quarter 0..3
    const int lane = tid & 63;
    const int r = lane & 15;
    const int u = lane >> 4;

    // weights: gates {2gp,2gp+1} x 2 n-frags x k-quarter kh -> 128 regs
    f16x8 wreg[2][2][8];
#pragma unroll
    for (int gl = 0; gl < 2; gl++)
#pragma unroll
        for (int n = 0; n < 2; n++) {
            const f16* wp = Whh + ((size_t)((2 * gp + gl) * NPAD + jc0 + n * 16 + r)) * NPAD +
                            (kh << 8) + (u << 3);
#pragma unroll
            for (int ks = 0; ks < 8; ks++) wreg[gl][n][ks] = *(const f16x8*)(wp + ks * 32);
        }

    const int eb = tid >> 4;          // epilogue batch row 0..31
    const int ej = (tid & 15) << 1;   // epilogue col pair
    float cv[2] = {0.f, 0.f};
    const size_t fl_base = (size_t)bt * TT * 4 * 32;
    const size_t preblk = (((size_t)bt * 32 + jt) * 4096) + (size_t)lane * 64 + gp * 32;

    auto LOADP = [&](int tindex, f16x8 (&pc)[4]) {
        if (kh == 0) {
            const f16* pp = pre2 + (size_t)tindex * 8 * 32 * 4096 + preblk;
#pragma unroll
            for (int c = 0; c < 4; c++) pc[c] = *(const f16x8*)(pp + c * 8);
        }
    };

    auto STEP = [&](int t, f16x8 (&pc)[4], f16x8 (&pn)[4]) {
        // 1) acc init from pre fragment regs (frees pc before h loads)
        f32x4 acc[2][2][2];  // [mi][gl][n]
#pragma unroll
        for (int mi = 0; mi < 2; mi++)
#pragma unroll
            for (int gl = 0; gl < 2; gl++)
#pragma unroll
                for (int n = 0; n < 2; n++)
#pragma unroll
                    for (int q = 0; q < 4; q++)
                        acc[mi][gl][n][q] = (kh == 0) ? (float)pc[gl * 2 + n][mi * 4 + q] : 0.f;

        // 2) prefetch next step's pre2 block
        LOADP(t + 1 < TT ? t + 1 : t, pn);

        if (t > 0) {
            // 3) per-quarter spin: wait for the 8 producers of quarter kh
            const unsigned* fq = flags + fl_base + ((size_t)(t - 1) * 4 + kh) * 32;
            while (__hip_atomic_load(fq, __ATOMIC_RELAXED, __HIP_MEMORY_SCOPE_AGENT) < 8u) {}
            asm volatile("" ::: "memory");
            // 4) h -> registers (A-fragments direct from L2; coalesced 16B/lane)
            const f16* hr = hall + (size_t)(t - 1) * NB * NPAD + (size_t)b0 * NPAD +
                            (kh << 8) + (u << 3);
            f16x8 hreg[2][8];
#pragma unroll
            for (int ks = 0; ks < 8; ks++) {
                hreg[0][ks] = *(const f16x8*)(hr + (size_t)r * NPAD + ks * 32);
                hreg[1][ks] = *(const f16x8*)(hr + (size_t)(16 + r) * NPAD + ks * 32);
            }
            // 5) MFMA: 64 per wave, all operands in registers
#pragma unroll
            for (int ks = 0; ks < 8; ks++) {
#pragma unroll
                for (int gl = 0; gl < 2; gl++)
#pragma unroll
                    for (int n = 0; n < 2; n++) {
                        acc[0][gl][n] = __builtin_amdgcn_mfma_f32_16x16x32_f16(
                            hreg[0][ks], wreg[gl][n][ks], acc[0][gl][n], 0, 0, 0);
                        acc[1][gl][n] = __builtin_amdgcn_mfma_f32_16x16x32_f16(
                            hreg[1][ks], wreg[gl][n][ks], acc[1][gl][n], 0, 0, 0);
                    }
            }
        }

        // 6) write this wave's k-partial to its own pl region
#pragma unroll
        for (int mi = 0; mi < 2; mi++)
#pragma unroll
            for (int gl = 0; gl < 2; gl++)
#pragma unroll
                for (int n = 0; n < 2; n++)
#pragma unroll
                    for (int q = 0; q < 4; q++)
                        pl[((kh * 4 + 2 * gp + gl) * 32 + mi * 16 + u * 4 + q) * 34 +
                           n * 16 + r] = acc[mi][gl][n][q];
        __syncthreads();  // B: partials ready

        // 7) cell update: thread -> (eb, ej..ej+1); gate = sum of 4 k-partials
        float gv[4][2];
#pragma unroll
        for (int gate = 0; gate < 4; gate++) {
            float2 s = make_float2(0.f, 0.f);
#pragma unroll
            for (int k2 = 0; k2 < 4; k2++) {
                float2 p = *(const float2*)&pl[((k2 * 4 + gate) * 32 + eb) * 34 + ej];
                s.x += p.x;
                s.y += p.y;
            }
            gv[gate][0] = s.x;
            gv[gate][1] = s.y;
        }
        float hvv[2];
#pragma unroll
        for (int q = 0; q < 2; q++) {
            float cn = sigmf_(gv[1][q]) * cv[q] + sigmf_(gv[0][q]) * tanhf_(gv[2][q]);
            hvv[q] = sigmf_(gv[3][q]) * tanhf_(cn);
            cv[q] = cn;
        }
        // 8) publish h via relaxed AGENT atomic store (coherence point)
        {
            union { f16 h2[2]; unsigned uu; } cvt;
            cvt.h2[0] = (f16)hvv[0];
            cvt.h2[1] = (f16)hvv[1];
            __hip_atomic_store(
                (unsigned*)(hall + ((size_t)t * NB + b0 + eb) * NPAD + jc0 + ej), cvt.uu,
                __ATOMIC_RELAXED, __HIP_MEMORY_SCOPE_AGENT);
        }
        __syncthreads();  // C: vmcnt drained -> h stores visible; pl reads done
        // 9) signal own quarter
        if (tid == 0)
            __hip_atomic_fetch_add(flags + fl_base + ((size_t)t * 4 + (jt >> 3)) * 32, 1u,
                                   __ATOMIC_RELAXED, __HIP_MEMORY_SCOPE_AGENT);
        // 10) output store AFTER the signal (nothing reads outl this dispatch)
        const int col = jc0 + ej;
        if (col < HID_) {
            *(float2*)(outl + ((size_t)(b0 + eb) * TT + t) * HID_ + col) =
                make_float2(hvv[0], hvv[1]);
        }
    };

    f16x8 pA[4] = {}, pB[4] = {};
    LOADP(0, pA);
    for (int t = 0; t < TT; t += 2) {
        STEP(t, pA, pB);
        if (t + 1 < TT) STEP(t + 1, pB, pA);
    }
}

extern "C" void kernel_launch(void* const* d_in, const int* in_sizes, int n_in,
                              void* d_out, int out_size, void* d_ws, size_t ws_size,
                              hipStream_t stream) {
    const float* enc_in = (const float*)d_in[0];
    const float* W_ih[3] = {(const float*)d_in[1], (const float*)d_in[5], (const float*)d_in[9]};
    const float* W_hh[3] = {(const float*)d_in[2], (const float*)d_in[6], (const float*)d_in[10]};
    const float* b_ih[3] = {(const float*)d_in[3], (const float*)d_in[7], (const float*)d_in[11]};
    const float* b_hh[3] = {(const float*)d_in[4], (const float*)d_in[8], (const float*)d_in[12]};
    float* out = (float*)d_out;

    char* ws = (char*)d_ws;
    size_t off = 0;
    auto alloc = [&](size_t bytes) {
        char* p = ws + off;
        off += (bytes + 255) & ~(size_t)255;
        return p;
    };
    f16* Wih_c[3];
    f16* Whh_c[3];
    Wih_c[0] = (f16*)alloc(4ull * NPAD * DIN * sizeof(f16));
    Whh_c[0] = (f16*)alloc(4ull * NPAD * NPAD * sizeof(f16));
    Wih_c[1] = (f16*)alloc(4ull * NPAD * NPAD * sizeof(f16));
    Whh_c[1] = (f16*)alloc(4ull * NPAD * NPAD * sizeof(f16));
    Wih_c[2] = (f16*)alloc(4ull * NPAD * NPAD * sizeof(f16));
    Whh_c[2] = (f16*)alloc(4ull * NPAD * NPAD * sizeof(f16));
    float* bias_c[3];
    for (int l = 0; l < 3; l++) bias_c[l] = (float*)alloc(4ull * NPAD * sizeof(float));
    f16* xbf = (f16*)alloc((size_t)TT * NB * DIN * sizeof(f16));
    f16* hall[3];
    for (int l = 0; l < 3; l++) hall[l] = (f16*)alloc((size_t)TT * NB * NPAD * sizeof(f16));
    f16* pre2 = (f16*)alloc((size_t)M_ALL * 4096 * sizeof(f16));
    // flags: [layer][bt][t][kq] padded to 128B each
    const size_t fl_layer = (size_t)8 * TT * 4 * 32;
    unsigned int* flags = (unsigned int*)alloc(3 * fl_layer * sizeof(unsigned int));

    hipMemsetAsync(flags, 0, 3 * fl_layer * sizeof(unsigned int), stream);

    conv_weight<<<512, 256, 0, stream>>>(W_ih[0], Wih_c[0], DIN, DIN);
    conv_weight<<<2048, 256, 0, stream>>>(W_hh[0], Whh_c[0], HID_, NPAD);
    conv_weight<<<2048, 256, 0, stream>>>(W_ih[1], Wih_c[1], HID_, NPAD);
    conv_weight<<<2048, 256, 0, stream>>>(W_hh[1], Whh_c[1], HID_, NPAD);
    conv_weight<<<2048, 256, 0, stream>>>(W_ih[2], Wih_c[2], HID_, NPAD);
    conv_weight<<<2048, 256, 0, stream>>>(W_hh[2], Whh_c[2], HID_, NPAD);
    conv_x<<<1024, 256, 0, stream>>>(enc_in, xbf);
    for (int l = 0; l < 3; l++)
        conv_bias<<<(4 * NPAD + 255) / 256, 256, 0, stream>>>(b_ih[l], b_hh[l], bias_c[l]);

    for (int l = 0; l < 3; l++) {
        if (l == 0)
            input_gemm<<<3136, 256, 0, stream>>>(xbf, DIN, DIN / 64, Wih_c[0], DIN,
                                                 bias_c[0], pre2);
        else
            input_gemm<<<3136, 256, 0, stream>>>(hall[l - 1], NPAD, NPAD / 64, Wih_c[l], NPAD,
                                                 bias_c[l], pre2);
        rec_persist<<<256, 512, 0, stream>>>(
            Whh_c[l], pre2, hall[l], out + (size_t)l * NB * TT * HID_,
            flags + (size_t)l * fl_layer);
    }
}

// Round 11
// 1121.933 us; speedup vs baseline: 1.2827x; 1.2827x over previous
//
#include <hip/hip_runtime.h>

#define HID_ 1000
#define NB 256
#define TT 49
#define DIN 192
#define NPAD 1024
#define M_ALL (TT * 256)  // 12544

typedef _Float16 f16;
typedef _Float16 f16x4 __attribute__((ext_vector_type(4)));
typedef _Float16 f16x8 __attribute__((ext_vector_type(8)));
typedef float f32x4 __attribute__((ext_vector_type(4)));
typedef const __attribute__((address_space(1))) unsigned int* gas_u32;
typedef __attribute__((address_space(3))) unsigned int* las_u32;

__device__ __forceinline__ float sigmf_(float x) {
    return 1.0f / (1.0f + __expf(-x));
}
__device__ __forceinline__ float tanhf_(float x) {
    float ax = fabsf(x);
    float e = __expf(-2.0f * ax);
    float t = (1.0f - e) / (1.0f + e);
    return copysignf(t, x);
}

// Convert fp32 weight [4*HID_][K] -> f16 [4][NPAD][KPADv], zero-padded.
__global__ void conv_weight(const float* __restrict__ src, f16* __restrict__ dst,
                            int K, int KPADv) {
    size_t total = 4ull * NPAD * KPADv;
    for (size_t idx = (size_t)blockIdx.x * blockDim.x + threadIdx.x; idx < total;
         idx += (size_t)gridDim.x * blockDim.x) {
        int kp = (int)(idx % KPADv);
        size_t rest = idx / KPADv;
        int np = (int)(rest % NPAD);
        int g = (int)(rest / NPAD);
        f16 v = (f16)0.0f;
        if (np < HID_ && kp < K) v = (f16)src[(size_t)(g * HID_ + np) * K + kp];
        dst[idx] = v;
    }
}

// enc_in [B][T][D] fp32 -> xbf [T][B][D] f16
__global__ void conv_x(const float* __restrict__ src, f16* __restrict__ dst) {
    size_t total = (size_t)TT * NB * DIN;
    for (size_t idx = (size_t)blockIdx.x * blockDim.x + threadIdx.x; idx < total;
         idx += (size_t)gridDim.x * blockDim.x) {
        int k = (int)(idx % DIN);
        size_t rest = idx / DIN;
        int b = (int)(rest % NB);
        int t = (int)(rest / NB);
        dst[idx] = (f16)src[((size_t)b * TT + t) * DIN + k];
    }
}

// bias_c[4][NPAD] fp32 = b_ih + b_hh (zero-padded)
__global__ void conv_bias(const float* __restrict__ bih, const float* __restrict__ bhh,
                          float* __restrict__ dst) {
    int idx = blockIdx.x * blockDim.x + threadIdx.x;
    if (idx < 4 * NPAD) {
        int np = idx & (NPAD - 1);
        int g = idx >> 10;
        float v = 0.0f;
        if (np < HID_) v = bih[g * HID_ + np] + bhh[g * HID_ + np];
        dst[idx] = v;
    }
}

// pre2 = A @ W^T + bias, stored in rec's fragment order (r6 layout):
// pre2[(((t*8+bt)*32+jt)*4+g)*1024 + l2*16 + (mi*8+n2*4+q)]  (f16)
// Epilogue stores f16x4 (q 0..3 contiguous). Validated in r8.
__global__ __launch_bounds__(256) void input_gemm(
    const f16* __restrict__ A, int lda, int kiters,
    const f16* __restrict__ W, int ldw,
    const float* __restrict__ bias,
    f16* __restrict__ pre2) {
    __shared__ f16 As[128 * 64];
    __shared__ f16 Bs[128 * 64];
    const int id = blockIdx.x;
    const int sw = (id & 7) * (gridDim.x >> 3) + (id >> 3);  // XCD swizzle (3136%8==0)
    const int m0 = (sw >> 5) << 7;
    const int n0 = (sw & 31) << 7;
    const int w = threadIdx.x >> 6;
    const int lane = threadIdx.x & 63;
    const int r = lane & 15;
    const int u = lane >> 4;
    const int kb8 = u << 3;  // frag k-offset (elements)
    const int wm = (w >> 1) << 6, wn = (w & 1) << 6;
    const int strow = (w << 5) + (lane >> 3);  // + q*8
    const int stcol = (lane & 7) << 3;         // elements

    f32x4 acc[4][4];
#pragma unroll
    for (int i = 0; i < 4; i++)
#pragma unroll
        for (int j = 0; j < 4; j++) acc[i][j] = (f32x4){0.f, 0.f, 0.f, 0.f};

    for (int kt = 0; kt < kiters; kt++) {
        const int k0 = kt << 6;
#pragma unroll
        for (int q = 0; q < 4; q++) {
            const int row = strow + (q << 3);
            const int cbase = ((w << 5) + (q << 3)) << 6;  // wave-uniform chunk base (elems)
            const f16* ga = A + (size_t)(m0 + row) * lda + k0 + stcol;
            const f16* gb = W + (size_t)(n0 + row) * ldw + k0 + stcol;
            __builtin_amdgcn_global_load_lds((gas_u32)ga, (las_u32)(As + cbase), 16, 0, 0);
            __builtin_amdgcn_global_load_lds((gas_u32)gb, (las_u32)(Bs + cbase), 16, 0, 0);
        }
        __syncthreads();
#pragma unroll
        for (int ks = 0; ks < 2; ks++) {
            f16x8 av[4], bv[4];
#pragma unroll
            for (int i = 0; i < 4; i++)
                av[i] = *(const f16x8*)(As + ((wm + i * 16 + r) << 6) + (ks << 5) + kb8);
#pragma unroll
            for (int j = 0; j < 4; j++)
                bv[j] = *(const f16x8*)(Bs + ((wn + j * 16 + r) << 6) + (ks << 5) + kb8);
#pragma unroll
            for (int i = 0; i < 4; i++)
#pragma unroll
                for (int j = 0; j < 4; j++)
                    acc[i][j] = __builtin_amdgcn_mfma_f32_16x16x32_f16(av[i], bv[j], acc[i][j], 0, 0, 0);
        }
        __syncthreads();
    }

#pragma unroll
    for (int j = 0; j < 4; j++) {
        const int gcol = n0 + wn + j * 16 + r;
        const float bj = bias[gcol];
        const int g = gcol >> 10, cl = gcol & 1023;
        const int jt2 = cl >> 5, c = cl & 31;
        const int n2 = c >> 4, r2 = c & 15;
        const int l2 = u * 16 + r2;
#pragma unroll
        for (int i = 0; i < 4; i++) {
            const int grow = m0 + wm + i * 16 + (u << 2);  // q=0 row
            const int t_ = grow >> 8;
            const int bt2 = (grow >> 5) & 7;
            const int mi = i & 1;
            f16x4 hv;
#pragma unroll
            for (int q = 0; q < 4; q++) hv[q] = (f16)(acc[i][j][q] + bj);
            *(f16x4*)(pre2 + ((((size_t)t_ * 8 + bt2) * 32 + jt2) * 4 + g) * 1024 +
                      l2 * 16 + mi * 8 + n2 * 4) = hv;
        }
    }
}

// Persistent per-layer recurrent kernel — consolidated r6 structure (best
// measured) with latency cuts only:
//  * wave-autonomous spin on the single group flag (no broadcast barrier)
//  * separate pl regions per kh-half + epilogue sum (no RMW phase/barrier)
//  * pl in its own LDS block (no h alias -> no alias barrier); 3 barriers/step
//  * vectorized epilogue reads; outl store after the signal
// 256 wgs x 512 thr, 8 waves (g 0..3, kh 0..1), 1 wg/CU.
__global__ __launch_bounds__(512, 2) void rec_persist(
    const f16* __restrict__ Whh, const f16* __restrict__ pre2,
    f16* __restrict__ hall, float* __restrict__ outl,
    unsigned int* __restrict__ flags) {
    __shared__ __align__(16) char smem[64 * 1024];  // h tile [32 rows][2048B] XOR-swizzled
    __shared__ float pl[2 * 4 * 32 * 34];           // [kh][gate][row][34] partials
    const int bid = blockIdx.x;
    const int bt = bid & 7;    // batch group (XCD-local under round-robin)
    const int jt = bid >> 3;   // column tile 0..31
    const int b0 = bt << 5;
    const int jc0 = jt << 5;
    const int tid = threadIdx.x;
    const int w = tid >> 6;
    const int g = w >> 1;      // gate 0..3
    const int kh = w & 1;      // K-half
    const int lane = tid & 63;
    const int r = lane & 15;
    const int u = lane >> 4;
    const int kbb = u << 4;    // bytes
    const int rbase = u << 2;
    const int swz = (r & 7) << 4;

    // load this wave's K-half of the weights into registers (once per layer)
    f16x8 wreg[2][16];
#pragma unroll
    for (int n = 0; n < 2; n++) {
        const f16* wp = Whh + ((size_t)(g * NPAD + jc0 + n * 16 + r)) * NPAD + (kh << 9) + (u << 3);
#pragma unroll
        for (int ks = 0; ks < 16; ks++) wreg[n][ks] = *(const f16x8*)(wp + ks * 32);
    }

    const int eb = tid >> 4;          // epilogue batch row 0..31
    const int ej = (tid & 15) << 1;   // epilogue col pair
    float cv[2] = {0.f, 0.f};
    unsigned int* myflags = flags + bt * TT;
    const size_t preblk = ((((size_t)bt) * 32 + jt) * 4 + g) * 1024 + lane * 16;

    auto LOADP = [&](int tindex, f16x8& pa, f16x8& pb) {
        if (kh == 0) {
            const f16* pp = pre2 + (size_t)tindex * 8 * 32 * 4 * 1024 + preblk;
            pa = *(const f16x8*)pp;
            pb = *(const f16x8*)(pp + 8);
        }
    };

    auto STEP = [&](int t, f16x8& pc0, f16x8& pc1, f16x8& pn0, f16x8& pn1) {
        // prefetch next step's pre2 block (hides under spin + MFMA)
        LOADP(t + 1 < TT ? t + 1 : t, pn0, pn1);

        if (t > 0) {
            // wave-autonomous spin on the single group flag line
            while (__hip_atomic_load(myflags + (t - 1), __ATOMIC_RELAXED,
                                     __HIP_MEMORY_SCOPE_AGENT) < 32u) {}
            asm volatile("" ::: "memory");
            // stage h = hall[t-1] rows b0..b0+31 -> LDS (XOR-swizzled rows)
            const f16* hread = hall + (size_t)(t - 1) * NB * NPAD;
#pragma unroll
            for (int i = 0; i < 8; i++) {
                int c = tid + (i << 9);
                int row = c >> 7;
                int cb = (c & 127) << 4;
                f16x8 v = *(const f16x8*)(hread + (size_t)(b0 + row) * NPAD + (cb >> 1));
                *(f16x8*)(smem + row * 2048 + (cb ^ ((row & 7) << 4))) = v;
            }
        }
        __syncthreads();  // B1: h tile staged

        // acc init: kh=0 from pre2 fragment regs, kh=1 zero
        f32x4 acc[2][2];  // [mi][n]
#pragma unroll
        for (int mi = 0; mi < 2; mi++)
#pragma unroll
            for (int n = 0; n < 2; n++)
#pragma unroll
                for (int q = 0; q < 4; q++) {
                    if (kh == 0)
                        acc[mi][n][q] = (float)(mi == 0 ? pc0[n * 4 + q] : pc1[n * 4 + q]);
                    else
                        acc[mi][n][q] = 0.f;
                }

        if (t > 0) {
#pragma unroll
            for (int ks = 0; ks < 16; ks++) {
                const int ksg = (kh << 4) + ks;
                f16x8 a0 = *(const f16x8*)(smem + r * 2048 + ((ksg * 64 + kbb) ^ swz));
                f16x8 a1 = *(const f16x8*)(smem + (16 + r) * 2048 + ((ksg * 64 + kbb) ^ swz));
                acc[0][0] = __builtin_amdgcn_mfma_f32_16x16x32_f16(a0, wreg[0][ks], acc[0][0], 0, 0, 0);
                acc[0][1] = __builtin_amdgcn_mfma_f32_16x16x32_f16(a0, wreg[1][ks], acc[0][1], 0, 0, 0);
                acc[1][0] = __builtin_amdgcn_mfma_f32_16x16x32_f16(a1, wreg[0][ks], acc[1][0], 0, 0, 0);
                acc[1][1] = __builtin_amdgcn_mfma_f32_16x16x32_f16(a1, wreg[1][ks], acc[1][1], 0, 0, 0);
            }
        }

        // write this K-half's partials to its own region (no RMW, no extra bar)
#pragma unroll
        for (int mi = 0; mi < 2; mi++)
#pragma unroll
            for (int n = 0; n < 2; n++)
#pragma unroll
                for (int q = 0; q < 4; q++)
                    pl[((kh * 4 + g) * 32 + mi * 16 + rbase + q) * 34 + n * 16 + r] =
                        acc[mi][n][q];
        __syncthreads();  // B2: partials ready

        // cell update: thread -> (eb, ej..ej+1); gate = kh0 + kh1 partials
        float hvv[2];
        {
            float gv[4][2];
#pragma unroll
            for (int gate = 0; gate < 4; gate++) {
                float2 p0 = *(const float2*)&pl[((0 * 4 + gate) * 32 + eb) * 34 + ej];
                float2 p1 = *(const float2*)&pl[((1 * 4 + gate) * 32 + eb) * 34 + ej];
                gv[gate][0] = p0.x + p1.x;
                gv[gate][1] = p0.y + p1.y;
            }
#pragma unroll
            for (int q = 0; q < 2; q++) {
                float cn = sigmf_(gv[1][q]) * cv[q] + sigmf_(gv[0][q]) * tanhf_(gv[2][q]);
                hvv[q] = sigmf_(gv[3][q]) * tanhf_(cn);
                cv[q] = cn;
            }
        }
        // publish h to hall[t] via relaxed AGENT atomic store (coherence point)
        {
            union { f16 h2[2]; unsigned uu; } cvt;
            cvt.h2[0] = (f16)hvv[0];
            cvt.h2[1] = (f16)hvv[1];
            __hip_atomic_store(
                (unsigned*)(hall + ((size_t)t * NB + b0 + eb) * NPAD + jc0 + ej), cvt.uu,
                __ATOMIC_RELAXED, __HIP_MEMORY_SCOPE_AGENT);
        }
        __syncthreads();  // B3: vmcnt drained -> h stores visible; pl reads done
        if (tid == 0)
            __hip_atomic_fetch_add(myflags + t, 1u, __ATOMIC_RELAXED, __HIP_MEMORY_SCOPE_AGENT);
        // output store AFTER the signal (nothing reads outl this dispatch)
        const int col = jc0 + ej;
        if (col < HID_) {
            *(float2*)(outl + ((size_t)(b0 + eb) * TT + t) * HID_ + col) =
                make_float2(hvv[0], hvv[1]);
        }
    };

    f16x8 pA0 = {}, pA1 = {}, pB0 = {}, pB1 = {};
    LOADP(0, pA0, pA1);
    for (int t = 0; t < TT; t += 2) {
        STEP(t, pA0, pA1, pB0, pB1);
        if (t + 1 < TT) STEP(t + 1, pB0, pB1, pA0, pA1);
    }
}

extern "C" void kernel_launch(void* const* d_in, const int* in_sizes, int n_in,
                              void* d_out, int out_size, void* d_ws, size_t ws_size,
                              hipStream_t stream) {
    const float* enc_in = (const float*)d_in[0];
    const float* W_ih[3] = {(const float*)d_in[1], (const float*)d_in[5], (const float*)d_in[9]};
    const float* W_hh[3] = {(const float*)d_in[2], (const float*)d_in[6], (const float*)d_in[10]};
    const float* b_ih[3] = {(const float*)d_in[3], (const float*)d_in[7], (const float*)d_in[11]};
    const float* b_hh[3] = {(const float*)d_in[4], (const float*)d_in[8], (const float*)d_in[12]};
    float* out = (float*)d_out;

    char* ws = (char*)d_ws;
    size_t off = 0;
    auto alloc = [&](size_t bytes) {
        char* p = ws + off;
        off += (bytes + 255) & ~(size_t)255;
        return p;
    };
    f16* Wih_c[3];
    f16* Whh_c[3];
    Wih_c[0] = (f16*)alloc(4ull * NPAD * DIN * sizeof(f16));
    Whh_c[0] = (f16*)alloc(4ull * NPAD * NPAD * sizeof(f16));
    Wih_c[1] = (f16*)alloc(4ull * NPAD * NPAD * sizeof(f16));
    Whh_c[1] = (f16*)alloc(4ull * NPAD * NPAD * sizeof(f16));
    Wih_c[2] = (f16*)alloc(4ull * NPAD * NPAD * sizeof(f16));
    Whh_c[2] = (f16*)alloc(4ull * NPAD * NPAD * sizeof(f16));
    float* bias_c[3];
    for (int l = 0; l < 3; l++) bias_c[l] = (float*)alloc(4ull * NPAD * sizeof(float));
    f16* xbf = (f16*)alloc((size_t)TT * NB * DIN * sizeof(f16));
    f16* hall[3];
    for (int l = 0; l < 3; l++) hall[l] = (f16*)alloc((size_t)TT * NB * NPAD * sizeof(f16));
    f16* pre2 = (f16*)alloc((size_t)M_ALL * 4096 * sizeof(f16));
    unsigned int* flags = (unsigned int*)alloc(3ull * 8 * TT * sizeof(unsigned int));

    hipMemsetAsync(flags, 0, 3ull * 8 * TT * sizeof(unsigned int), stream);

    conv_weight<<<512, 256, 0, stream>>>(W_ih[0], Wih_c[0], DIN, DIN);
    conv_weight<<<2048, 256, 0, stream>>>(W_hh[0], Whh_c[0], HID_, NPAD);
    conv_weight<<<2048, 256, 0, stream>>>(W_ih[1], Wih_c[1], HID_, NPAD);
    conv_weight<<<2048, 256, 0, stream>>>(W_hh[1], Whh_c[1], HID_, NPAD);
    conv_weight<<<2048, 256, 0, stream>>>(W_ih[2], Wih_c[2], HID_, NPAD);
    conv_weight<<<2048, 256, 0, stream>>>(W_hh[2], Whh_c[2], HID_, NPAD);
    conv_x<<<1024, 256, 0, stream>>>(enc_in, xbf);
    for (int l = 0; l < 3; l++)
        conv_bias<<<(4 * NPAD + 255) / 256, 256, 0, stream>>>(b_ih[l], b_hh[l], bias_c[l]);

    for (int l = 0; l < 3; l++) {
        if (l == 0)
            input_gemm<<<3136, 256, 0, stream>>>(xbf, DIN, DIN / 64, Wih_c[0], DIN,
                                                 bias_c[0], pre2);
        else
            input_gemm<<<3136, 256, 0, stream>>>(hall[l - 1], NPAD, NPAD / 64, Wih_c[l], NPAD,
                                                 bias_c[l], pre2);
        rec_persist<<<256, 512, 0, stream>>>(
            Whh_c[l], pre2, hall[l], out + (size_t)l * NB * TT * HID_,
            flags + (size_t)l * 8 * TT);
    }
}

// Round 12
// 1096.509 us; speedup vs baseline: 1.3124x; 1.0232x over previous
//
#include <hip/hip_runtime.h>

#define HID_ 1000
#define NB 256
#define TT 49
#define DIN 192
#define NPAD 1024
#define M_ALL (TT * 256)  // 12544

typedef _Float16 f16;
typedef _Float16 f16x4 __attribute__((ext_vector_type(4)));
typedef _Float16 f16x8 __attribute__((ext_vector_type(8)));
typedef float f32x4 __attribute__((ext_vector_type(4)));
typedef const __attribute__((address_space(1))) unsigned int* gas_u32;
typedef __attribute__((address_space(3))) unsigned int* las_u32;

__device__ __forceinline__ float sigmf_(float x) {
    return 1.0f / (1.0f + __expf(-x));
}
__device__ __forceinline__ float tanhf_(float x) {
    float ax = fabsf(x);
    float e = __expf(-2.0f * ax);
    float t = (1.0f - e) / (1.0f + e);
    return copysignf(t, x);
}

// Vectorized weight convert: fp32 [4*HID_][K] -> f16 [4][1024][KPADv], zero-pad.
// One thread per 8 contiguous k (float4 x2 load, f16x8 store). K % 8 == 0.
__global__ __launch_bounds__(256) void conv_weight_v(
    const float* __restrict__ src, f16* __restrict__ dst, int K, int KPADv, int total8) {
    int idx = blockIdx.x * blockDim.x + threadIdx.x;
    if (idx >= total8) return;
    const int kpw = KPADv >> 3;
    const int kp = (idx % kpw) << 3;
    const int rest = idx / kpw;          // g*1024 + np
    const int np = rest & 1023;
    const int g = rest >> 10;
    f16x8 v = {};
    if (np < HID_ && kp < K) {
        const float* sp = src + (size_t)(g * HID_ + np) * K + kp;
        float4 a = *(const float4*)sp;
        float4 b = *(const float4*)(sp + 4);
        v[0] = (f16)a.x; v[1] = (f16)a.y; v[2] = (f16)a.z; v[3] = (f16)a.w;
        v[4] = (f16)b.x; v[5] = (f16)b.y; v[6] = (f16)b.z; v[7] = (f16)b.w;
    }
    *(f16x8*)(dst + (size_t)rest * KPADv + kp) = v;
}

// Vectorized enc_in transpose-convert: [B][T][D] fp32 -> [T][B][D] f16.
// One thread per 8 contiguous k. total8 = TT*NB*(DIN/8).
__global__ __launch_bounds__(256) void conv_x_v(
    const float* __restrict__ src, f16* __restrict__ dst, int total8) {
    int idx = blockIdx.x * blockDim.x + threadIdx.x;
    if (idx >= total8) return;
    const int kp = (idx % (DIN / 8)) << 3;
    const int rest = idx / (DIN / 8);    // t*NB + b
    const int b = rest & 255;
    const int t = rest >> 8;
    const float* sp = src + ((size_t)b * TT + t) * DIN + kp;
    float4 a = *(const float4*)sp;
    float4 c = *(const float4*)(sp + 4);
    f16x8 v;
    v[0] = (f16)a.x; v[1] = (f16)a.y; v[2] = (f16)a.z; v[3] = (f16)a.w;
    v[4] = (f16)c.x; v[5] = (f16)c.y; v[6] = (f16)c.z; v[7] = (f16)c.w;
    *(f16x8*)(dst + (size_t)rest * DIN + kp) = v;
}

// bias_c[4][NPAD] fp32 = b_ih + b_hh (zero-padded)
__global__ void conv_bias(const float* __restrict__ bih, const float* __restrict__ bhh,
                          float* __restrict__ dst) {
    int idx = blockIdx.x * blockDim.x + threadIdx.x;
    if (idx < 4 * NPAD) {
        int np = idx & (NPAD - 1);
        int g = idx >> 10;
        float v = 0.0f;
        if (np < HID_) v = bih[g * HID_ + np] + bhh[g * HID_ + np];
        dst[idx] = v;
    }
}

// pre2 = A @ W^T + bias, stored in rec's fragment order (r6 layout):
// pre2[(((t*8+bt)*32+jt)*4+g)*1024 + l2*16 + (mi*8+n2*4+q)]  (f16)
__global__ __launch_bounds__(256) void input_gemm(
    const f16* __restrict__ A, int lda, int kiters,
    const f16* __restrict__ W, int ldw,
    const float* __restrict__ bias,
    f16* __restrict__ pre2) {
    __shared__ f16 As[128 * 64];
    __shared__ f16 Bs[128 * 64];
    const int id = blockIdx.x;
    const int sw = (id & 7) * (gridDim.x >> 3) + (id >> 3);  // XCD swizzle (3136%8==0)
    const int m0 = (sw >> 5) << 7;
    const int n0 = (sw & 31) << 7;
    const int w = threadIdx.x >> 6;
    const int lane = threadIdx.x & 63;
    const int r = lane & 15;
    const int u = lane >> 4;
    const int kb8 = u << 3;  // frag k-offset (elements)
    const int wm = (w >> 1) << 6, wn = (w & 1) << 6;
    const int strow = (w << 5) + (lane >> 3);  // + q*8
    const int stcol = (lane & 7) << 3;         // elements

    f32x4 acc[4][4];
#pragma unroll
    for (int i = 0; i < 4; i++)
#pragma unroll
        for (int j = 0; j < 4; j++) acc[i][j] = (f32x4){0.f, 0.f, 0.f, 0.f};

    for (int kt = 0; kt < kiters; kt++) {
        const int k0 = kt << 6;
#pragma unroll
        for (int q = 0; q < 4; q++) {
            const int row = strow + (q << 3);
            const int cbase = ((w << 5) + (q << 3)) << 6;  // wave-uniform chunk base (elems)
            const f16* ga = A + (size_t)(m0 + row) * lda + k0 + stcol;
            const f16* gb = W + (size_t)(n0 + row) * ldw + k0 + stcol;
            __builtin_amdgcn_global_load_lds((gas_u32)ga, (las_u32)(As + cbase), 16, 0, 0);
            __builtin_amdgcn_global_load_lds((gas_u32)gb, (las_u32)(Bs + cbase), 16, 0, 0);
        }
        __syncthreads();
#pragma unroll
        for (int ks = 0; ks < 2; ks++) {
            f16x8 av[4], bv[4];
#pragma unroll
            for (int i = 0; i < 4; i++)
                av[i] = *(const f16x8*)(As + ((wm + i * 16 + r) << 6) + (ks << 5) + kb8);
#pragma unroll
            for (int j = 0; j < 4; j++)
                bv[j] = *(const f16x8*)(Bs + ((wn + j * 16 + r) << 6) + (ks << 5) + kb8);
#pragma unroll
            for (int i = 0; i < 4; i++)
#pragma unroll
                for (int j = 0; j < 4; j++)
                    acc[i][j] = __builtin_amdgcn_mfma_f32_16x16x32_f16(av[i], bv[j], acc[i][j], 0, 0, 0);
        }
        __syncthreads();
    }

#pragma unroll
    for (int j = 0; j < 4; j++) {
        const int gcol = n0 + wn + j * 16 + r;
        const float bj = bias[gcol];
        const int g = gcol >> 10, cl = gcol & 1023;
        const int jt2 = cl >> 5, c = cl & 31;
        const int n2 = c >> 4, r2 = c & 15;
        const int l2 = u * 16 + r2;
#pragma unroll
        for (int i = 0; i < 4; i++) {
            const int grow = m0 + wm + i * 16 + (u << 2);  // q=0 row
            const int t_ = grow >> 8;
            const int bt2 = (grow >> 5) & 7;
            const int mi = i & 1;
            f16x4 hv;
#pragma unroll
            for (int q = 0; q < 4; q++) hv[q] = (f16)(acc[i][j][q] + bj);
            *(f16x4*)(pre2 + ((((size_t)t_ * 8 + bt2) * 32 + jt2) * 4 + g) * 1024 +
                      l2 * 16 + mi * 8 + n2 * 4) = hv;
        }
    }
}

// Persistent per-layer recurrent kernel — r11 structure verbatim (best measured).
__global__ __launch_bounds__(512, 2) void rec_persist(
    const f16* __restrict__ Whh, const f16* __restrict__ pre2,
    f16* __restrict__ hall, float* __restrict__ outl,
    unsigned int* __restrict__ flags) {
    __shared__ __align__(16) char smem[64 * 1024];  // h tile [32 rows][2048B] XOR-swizzled
    __shared__ float pl[2 * 4 * 32 * 34];           // [kh][gate][row][34] partials
    const int bid = blockIdx.x;
    const int bt = bid & 7;    // batch group (XCD-local under round-robin)
    const int jt = bid >> 3;   // column tile 0..31
    const int b0 = bt << 5;
    const int jc0 = jt << 5;
    const int tid = threadIdx.x;
    const int w = tid >> 6;
    const int g = w >> 1;      // gate 0..3
    const int kh = w & 1;      // K-half
    const int lane = tid & 63;
    const int r = lane & 15;
    const int u = lane >> 4;
    const int kbb = u << 4;    // bytes
    const int rbase = u << 2;
    const int swz = (r & 7) << 4;

    // load this wave's K-half of the weights into registers (once per layer)
    f16x8 wreg[2][16];
#pragma unroll
    for (int n = 0; n < 2; n++) {
        const f16* wp = Whh + ((size_t)(g * NPAD + jc0 + n * 16 + r)) * NPAD + (kh << 9) + (u << 3);
#pragma unroll
        for (int ks = 0; ks < 16; ks++) wreg[n][ks] = *(const f16x8*)(wp + ks * 32);
    }

    const int eb = tid >> 4;          // epilogue batch row 0..31
    const int ej = (tid & 15) << 1;   // epilogue col pair
    float cv[2] = {0.f, 0.f};
    unsigned int* myflags = flags + bt * TT;
    const size_t preblk = ((((size_t)bt) * 32 + jt) * 4 + g) * 1024 + lane * 16;

    auto LOADP = [&](int tindex, f16x8& pa, f16x8& pb) {
        if (kh == 0) {
            const f16* pp = pre2 + (size_t)tindex * 8 * 32 * 4 * 1024 + preblk;
            pa = *(const f16x8*)pp;
            pb = *(const f16x8*)(pp + 8);
        }
    };

    auto STEP = [&](int t, f16x8& pc0, f16x8& pc1, f16x8& pn0, f16x8& pn1) {
        // prefetch next step's pre2 block (hides under spin + MFMA)
        LOADP(t + 1 < TT ? t + 1 : t, pn0, pn1);

        if (t > 0) {
            // wave-autonomous spin on the single group flag line
            while (__hip_atomic_load(myflags + (t - 1), __ATOMIC_RELAXED,
                                     __HIP_MEMORY_SCOPE_AGENT) < 32u) {}
            asm volatile("" ::: "memory");
            // stage h = hall[t-1] rows b0..b0+31 -> LDS (XOR-swizzled rows)
            const f16* hread = hall + (size_t)(t - 1) * NB * NPAD;
#pragma unroll
            for (int i = 0; i < 8; i++) {
                int c = tid + (i << 9);
                int row = c >> 7;
                int cb = (c & 127) << 4;
                f16x8 v = *(const f16x8*)(hread + (size_t)(b0 + row) * NPAD + (cb >> 1));
                *(f16x8*)(smem + row * 2048 + (cb ^ ((row & 7) << 4))) = v;
            }
        }
        __syncthreads();  // B1: h tile staged

        // acc init: kh=0 from pre2 fragment regs, kh=1 zero
        f32x4 acc[2][2];  // [mi][n]
#pragma unroll
        for (int mi = 0; mi < 2; mi++)
#pragma unroll
            for (int n = 0; n < 2; n++)
#pragma unroll
                for (int q = 0; q < 4; q++) {
                    if (kh == 0)
                        acc[mi][n][q] = (float)(mi == 0 ? pc0[n * 4 + q] : pc1[n * 4 + q]);
                    else
                        acc[mi][n][q] = 0.f;
                }

        if (t > 0) {
#pragma unroll
            for (int ks = 0; ks < 16; ks++) {
                const int ksg = (kh << 4) + ks;
                f16x8 a0 = *(const f16x8*)(smem + r * 2048 + ((ksg * 64 + kbb) ^ swz));
                f16x8 a1 = *(const f16x8*)(smem + (16 + r) * 2048 + ((ksg * 64 + kbb) ^ swz));
                acc[0][0] = __builtin_amdgcn_mfma_f32_16x16x32_f16(a0, wreg[0][ks], acc[0][0], 0, 0, 0);
                acc[0][1] = __builtin_amdgcn_mfma_f32_16x16x32_f16(a0, wreg[1][ks], acc[0][1], 0, 0, 0);
                acc[1][0] = __builtin_amdgcn_mfma_f32_16x16x32_f16(a1, wreg[0][ks], acc[1][0], 0, 0, 0);
                acc[1][1] = __builtin_amdgcn_mfma_f32_16x16x32_f16(a1, wreg[1][ks], acc[1][1], 0, 0, 0);
            }
        }

        // write this K-half's partials to its own region (no RMW, no extra bar)
#pragma unroll
        for (int mi = 0; mi < 2; mi++)
#pragma unroll
            for (int n = 0; n < 2; n++)
#pragma unroll
                for (int q = 0; q < 4; q++)
                    pl[((kh * 4 + g) * 32 + mi * 16 + rbase + q) * 34 + n * 16 + r] =
                        acc[mi][n][q];
        __syncthreads();  // B2: partials ready

        // cell update: thread -> (eb, ej..ej+1); gate = kh0 + kh1 partials
        float hvv[2];
        {
            float gv[4][2];
#pragma unroll
            for (int gate = 0; gate < 4; gate++) {
                float2 p0 = *(const float2*)&pl[((0 * 4 + gate) * 32 + eb) * 34 + ej];
                float2 p1 = *(const float2*)&pl[((1 * 4 + gate) * 32 + eb) * 34 + ej];
                gv[gate][0] = p0.x + p1.x;
                gv[gate][1] = p0.y + p1.y;
            }
#pragma unroll
            for (int q = 0; q < 2; q++) {
                float cn = sigmf_(gv[1][q]) * cv[q] + sigmf_(gv[0][q]) * tanhf_(gv[2][q]);
                hvv[q] = sigmf_(gv[3][q]) * tanhf_(cn);
                cv[q] = cn;
            }
        }
        // publish h to hall[t] via relaxed AGENT atomic store (coherence point)
        {
            union { f16 h2[2]; unsigned uu; } cvt;
            cvt.h2[0] = (f16)hvv[0];
            cvt.h2[1] = (f16)hvv[1];
            __hip_atomic_store(
                (unsigned*)(hall + ((size_t)t * NB + b0 + eb) * NPAD + jc0 + ej), cvt.uu,
                __ATOMIC_RELAXED, __HIP_MEMORY_SCOPE_AGENT);
        }
        __syncthreads();  // B3: vmcnt drained -> h stores visible; pl reads done
        if (tid == 0)
            __hip_atomic_fetch_add(myflags + t, 1u, __ATOMIC_RELAXED, __HIP_MEMORY_SCOPE_AGENT);
        // output store AFTER the signal (nothing reads outl this dispatch)
        const int col = jc0 + ej;
        if (col < HID_) {
            *(float2*)(outl + ((size_t)(b0 + eb) * TT + t) * HID_ + col) =
                make_float2(hvv[0], hvv[1]);
        }
    };

    f16x8 pA0 = {}, pA1 = {}, pB0 = {}, pB1 = {};
    LOADP(0, pA0, pA1);
    for (int t = 0; t < TT; t += 2) {
        STEP(t, pA0, pA1, pB0, pB1);
        if (t + 1 < TT) STEP(t + 1, pB0, pB1, pA0, pA1);
    }
}

extern "C" void kernel_launch(void* const* d_in, const int* in_sizes, int n_in,
                              void* d_out, int out_size, void* d_ws, size_t ws_size,
                              hipStream_t stream) {
    const float* enc_in = (const float*)d_in[0];
    const float* W_ih[3] = {(const float*)d_in[1], (const float*)d_in[5], (const float*)d_in[9]};
    const float* W_hh[3] = {(const float*)d_in[2], (const float*)d_in[6], (const float*)d_in[10]};
    const float* b_ih[3] = {(const float*)d_in[3], (const float*)d_in[7], (const float*)d_in[11]};
    const float* b_hh[3] = {(const float*)d_in[4], (const float*)d_in[8], (const float*)d_in[12]};
    float* out = (float*)d_out;

    char* ws = (char*)d_ws;
    size_t off = 0;
    auto alloc = [&](size_t bytes) {
        char* p = ws + off;
        off += (bytes + 255) & ~(size_t)255;
        return p;
    };
    f16* Wih_c[3];
    f16* Whh_c[3];
    Wih_c[0] = (f16*)alloc(4ull * NPAD * DIN * sizeof(f16));
    Whh_c[0] = (f16*)alloc(4ull * NPAD * NPAD * sizeof(f16));
    Wih_c[1] = (f16*)alloc(4ull * NPAD * NPAD * sizeof(f16));
    Whh_c[1] = (f16*)alloc(4ull * NPAD * NPAD * sizeof(f16));
    Wih_c[2] = (f16*)alloc(4ull * NPAD * NPAD * sizeof(f16));
    Whh_c[2] = (f16*)alloc(4ull * NPAD * NPAD * sizeof(f16));
    float* bias_c[3];
    for (int l = 0; l < 3; l++) bias_c[l] = (float*)alloc(4ull * NPAD * sizeof(float));
    f16* xbf = (f16*)alloc((size_t)TT * NB * DIN * sizeof(f16));
    f16* hall[3];
    for (int l = 0; l < 3; l++) hall[l] = (f16*)alloc((size_t)TT * NB * NPAD * sizeof(f16));
    f16* pre2 = (f16*)alloc((size_t)M_ALL * 4096 * sizeof(f16));
    unsigned int* flags = (unsigned int*)alloc(3ull * 8 * TT * sizeof(unsigned int));

    hipMemsetAsync(flags, 0, 3ull * 8 * TT * sizeof(unsigned int), stream);

    // vectorized weight converts: total8 = 4*1024*KPADv/8
    {
        int t8_l0 = 4 * NPAD * DIN / 8;      // 98304
        conv_weight_v<<<(t8_l0 + 255) / 256, 256, 0, stream>>>(W_ih[0], Wih_c[0], DIN, DIN, t8_l0);
        int t8 = 4 * NPAD * NPAD / 8;        // 524288
        conv_weight_v<<<(t8 + 255) / 256, 256, 0, stream>>>(W_hh[0], Whh_c[0], HID_, NPAD, t8);
        conv_weight_v<<<(t8 + 255) / 256, 256, 0, stream>>>(W_ih[1], Wih_c[1], HID_, NPAD, t8);
        conv_weight_v<<<(t8 + 255) / 256, 256, 0, stream>>>(W_hh[1], Whh_c[1], HID_, NPAD, t8);
        conv_weight_v<<<(t8 + 255) / 256, 256, 0, stream>>>(W_ih[2], Wih_c[2], HID_, NPAD, t8);
        conv_weight_v<<<(t8 + 255) / 256, 256, 0, stream>>>(W_hh[2], Whh_c[2], HID_, NPAD, t8);
    }
    {
        int t8x = TT * NB * (DIN / 8);       // 301056
        conv_x_v<<<(t8x + 255) / 256, 256, 0, stream>>>(enc_in, xbf, t8x);
    }
    for (int l = 0; l < 3; l++)
        conv_bias<<<(4 * NPAD + 255) / 256, 256, 0, stream>>>(b_ih[l], b_hh[l], bias_c[l]);

    for (int l = 0; l < 3; l++) {
        if (l == 0)
            input_gemm<<<3136, 256, 0, stream>>>(xbf, DIN, DIN / 64, Wih_c[0], DIN,
                                                 bias_c[0], pre2);
        else
            input_gemm<<<3136, 256, 0, stream>>>(hall[l - 1], NPAD, NPAD / 64, Wih_c[l], NPAD,
                                                 bias_c[l], pre2);
        rec_persist<<<256, 512, 0, stream>>>(
            Whh_c[l], pre2, hall[l], out + (size_t)l * NB * TT * HID_,
            flags + (size_t)l * 8 * TT);
    }
}